// Round 8
// baseline (619.672 us; speedup 1.0000x reference)
//
#include <hip/hip_runtime.h>
#include <math.h>

#define WIDTH 256
typedef unsigned short u16;
typedef unsigned int u32;
typedef __attribute__((ext_vector_type(4))) float f32x4;
typedef __attribute__((ext_vector_type(8))) short bf16x8;

__device__ __forceinline__ float gelu_exact(float v) {
    return 0.5f * v * (1.0f + erff(v * 0.70710678118654752f));
}
__device__ __forceinline__ u16 f2b(float x) {   // f32 -> bf16 RTNE
    u32 u = __builtin_bit_cast(u32, x);
    return (u16)((u + 0x7fffu + ((u >> 16) & 1u)) >> 16);
}
__device__ __forceinline__ float b2f_lo(u32 v) {
    return __builtin_bit_cast(float, v << 16);
}
__device__ __forceinline__ float b2f_hi(u32 v) {
    return __builtin_bit_cast(float, v & 0xffff0000u);
}
__device__ __forceinline__ u32 pack2(float a, float b) {
    return (u32)f2b(a) | ((u32)f2b(b) << 16);
}

// ---------------- CSR build ----------------
__global__ void k_hist(const int* __restrict__ col, int* __restrict__ deg, int E) {
    int i = blockIdx.x * blockDim.x + threadIdx.x;
    if (i < E) atomicAdd(&deg[col[i]], 1);
}

__global__ __launch_bounds__(256) void k_scan1(const int* __restrict__ deg, int* __restrict__ off,
                                               int* __restrict__ part, float* __restrict__ dis, int N) {
    __shared__ int buf[256];
    const int t = threadIdx.x;
    const int gid = blockIdx.x * 256 + t;
    const int v = (gid < N) ? deg[gid] : 0;
    if (gid < N) dis[gid] = rsqrtf(1.0f + (float)v);
    buf[t] = v;
    __syncthreads();
#pragma unroll
    for (int d = 1; d < 256; d <<= 1) {
        int add = (t >= d) ? buf[t - d] : 0;
        __syncthreads();
        buf[t] += add;
        __syncthreads();
    }
    if (gid < N) off[gid] = buf[t] - v;
    if (t == 255) part[blockIdx.x] = buf[255];
}

__global__ __launch_bounds__(256) void k_scan2(int* __restrict__ part, int NB) {
    __shared__ int buf[256];
    const int t = threadIdx.x;
    int v = (t < NB) ? part[t] : 0;
    buf[t] = v;
    __syncthreads();
#pragma unroll
    for (int d = 1; d < 256; d <<= 1) {
        int add = (t >= d) ? buf[t - d] : 0;
        __syncthreads();
        buf[t] += add;
        __syncthreads();
    }
    if (t < NB) part[t] = buf[t] - v;
}

__global__ __launch_bounds__(256) void k_scan3(int* __restrict__ off, const int* __restrict__ part,
                                               int* __restrict__ cursor, int N, int E) {
    const int gid = blockIdx.x * 256 + threadIdx.x;
    if (gid < N) {
        int o = off[gid] + part[blockIdx.x];
        off[gid] = o;
        cursor[gid] = o;
    }
    if (gid == 0) off[N] = E;
}

__global__ void k_fill(const int* __restrict__ row, const int* __restrict__ col,
                       int* __restrict__ cursor, int* __restrict__ csr_src, int E) {
    int i = blockIdx.x * blockDim.x + threadIdx.x;
    if (i < E) {
        int pos = atomicAdd(&cursor[col[i]], 1);
        csr_src[pos] = row[i];
    }
}

// ---------------- merged prep: WgT transpose + WfT copy + x->bf16 ----------------
__global__ void k_prep(const float* __restrict__ Wg, const float* __restrict__ Wf,
                       const float* __restrict__ x,
                       u16* __restrict__ WgT, u16* __restrict__ WfT,
                       u16* __restrict__ xb, int total8) {
    int idx = blockIdx.x * blockDim.x + threadIdx.x;
    if (idx < 4 * 65536) {
        int l = idx >> 16;
        int k = (idx >> 8) & 255;
        int n = idx & 255;
        WgT[(size_t)l * 65536 + (size_t)n * 256 + k] = f2b(Wg[idx]);
    } else if (idx < 4 * 65536 + 256 * 64) {
        int j = idx - 4 * 65536;
        WfT[j] = f2b(Wf[j]);   // Wf already [n][k]
    } else {
        int i = idx - (4 * 65536 + 256 * 64);
        if (i < total8) {
            const float4 v0 = *reinterpret_cast<const float4*>(&x[(size_t)i * 8]);
            const float4 v1 = *reinterpret_cast<const float4*>(&x[(size_t)i * 8 + 4]);
            uint4 o;
            o.x = pack2(v0.x, v0.y);
            o.y = pack2(v0.z, v0.w);
            o.z = pack2(v1.x, v1.y);
            o.w = pack2(v1.z, v1.w);
            *reinterpret_cast<uint4*>(&xb[(size_t)i * 8]) = o;
        }
    }
}

// ---------------- foot MFMA GEMM (verified round-6 structure, KDIM=64) ----------------
template <int KDIM>
__global__ __launch_bounds__(256) void k_gemm_foot(const u16* __restrict__ A,
                                                   const u16* __restrict__ BT,
                                                   const float* __restrict__ bias,
                                                   u16* __restrict__ Cb,
                                                   float* __restrict__ Cf) {
    __shared__ u16 As[64 * 64];
    __shared__ u16 Bs[256 * 64];

    const int tid = threadIdx.x;
    const int w = tid >> 6;
    const int l = tid & 63;
    const int m0 = blockIdx.x * 64;

    const int lr = l >> 3;
    const int lc = l & 7;
    const int src_slot = lc ^ lr;

    f32x4 acc[4][4] = {};

#pragma unroll
    for (int ks = 0; ks < KDIM / 64; ++ks) {
        const int k0 = ks * 64;
#pragma unroll
        for (int i = 0; i < 2; ++i) {
            const u16* asrc = A + (size_t)(m0 + 16 * w + 8 * i + lr) * KDIM + k0 + src_slot * 8;
            __builtin_amdgcn_global_load_lds(
                (const __attribute__((address_space(1))) u32*)asrc,
                (__attribute__((address_space(3))) u32*)(As + (16 * w + 8 * i) * 64), 16, 0, 0);
        }
#pragma unroll
        for (int j = 0; j < 8; ++j) {
            const u16* bsrc = BT + (size_t)(64 * w + 8 * j + lr) * KDIM + k0 + src_slot * 8;
            __builtin_amdgcn_global_load_lds(
                (const __attribute__((address_space(1))) u32*)bsrc,
                (__attribute__((address_space(3))) u32*)(Bs + (64 * w + 8 * j) * 64), 16, 0, 0);
        }
        asm volatile("s_waitcnt vmcnt(0)" ::: "memory");
        __syncthreads();

        bf16x8 a[4][2], b[4][2];
#pragma unroll
        for (int fr = 0; fr < 4; ++fr) {
            const int row = fr * 16 + (l & 15);
#pragma unroll
            for (int kk = 0; kk < 2; ++kk)
                a[fr][kk] = *reinterpret_cast<const bf16x8*>(
                    &As[row * 64 + ((kk * 4 + (l >> 4)) ^ (row & 7)) * 8]);
        }
#pragma unroll
        for (int fc = 0; fc < 4; ++fc) {
            const int row = 64 * w + fc * 16 + (l & 15);
#pragma unroll
            for (int kk = 0; kk < 2; ++kk)
                b[fc][kk] = *reinterpret_cast<const bf16x8*>(
                    &Bs[row * 64 + ((kk * 4 + (l >> 4)) ^ (row & 7)) * 8]);
        }
#pragma unroll
        for (int fr = 0; fr < 4; ++fr)
#pragma unroll
            for (int fc = 0; fc < 4; ++fc) {
                acc[fr][fc] = __builtin_amdgcn_mfma_f32_16x16x32_bf16(a[fr][0], b[fc][0], acc[fr][fc], 0, 0, 0);
                acc[fr][fc] = __builtin_amdgcn_mfma_f32_16x16x32_bf16(a[fr][1], b[fc][1], acc[fr][fc], 0, 0, 0);
            }
        __syncthreads();
    }

    const int r0 = (l >> 4) * 4;
    const int ci = l & 15;
#pragma unroll
    for (int fr = 0; fr < 4; ++fr)
#pragma unroll
        for (int fc = 0; fc < 4; ++fc) {
            const int col = w * 64 + fc * 16 + ci;
#pragma unroll
            for (int r = 0; r < 4; ++r) {
                const int row = m0 + fr * 16 + r0 + r;
                const float o = gelu_exact(acc[fr][fc][r] + bias[col]);
                Cf[(size_t)row * WIDTH + col] = o;
                Cb[(size_t)row * WIDTH + col] = f2b(o);
            }
        }
}

// ---------------- fused GCN layer: y = Â(hin) in LDS, then h += y@W + bg ----------------
// hin and hout MUST be distinct buffers (ping-pong): other blocks gather-read hin rows
// this block owns, while this block writes hout. 64 dest nodes per block.
__global__ __launch_bounds__(256) void k_layer(const int* __restrict__ off,
                                               const int* __restrict__ csr_src,
                                               const float* __restrict__ dis,
                                               const u16* __restrict__ hin,
                                               const u16* __restrict__ WgT_l,
                                               const float* __restrict__ bg_l,
                                               float* __restrict__ h,
                                               u16* __restrict__ hout) {
    __shared__ u16 Ys[64 * 256];   // [row][chan], 16B slots swizzled: slot ^= row&7

    const int tid = threadIdx.x;
    const int m0 = blockIdx.x * 64;

    // ---- phase 1: gather-aggregate ----
    {
        const int g = tid >> 5;
        const int hl = tid & 31;
#pragma unroll 1
        for (int t = 0; t < 8; ++t) {
            const int node = m0 + g * 8 + t;
            const int e0 = off[node];
            const int e1 = off[node + 1];
            const float di = dis[node];

            float acc[8];
            // self-loop
            {
                const uint4 v = *reinterpret_cast<const uint4*>(&hin[(size_t)node * WIDTH + hl * 8]);
                acc[0] = di * b2f_lo(v.x); acc[1] = di * b2f_hi(v.x);
                acc[2] = di * b2f_lo(v.y); acc[3] = di * b2f_hi(v.y);
                acc[4] = di * b2f_lo(v.z); acc[5] = di * b2f_hi(v.z);
                acc[6] = di * b2f_lo(v.w); acc[7] = di * b2f_hi(v.w);
            }

#define EDGE_FMA(vv, dd_)                          \
    acc[0] = fmaf(dd_, b2f_lo(vv.x), acc[0]);      \
    acc[1] = fmaf(dd_, b2f_hi(vv.x), acc[1]);      \
    acc[2] = fmaf(dd_, b2f_lo(vv.y), acc[2]);      \
    acc[3] = fmaf(dd_, b2f_hi(vv.y), acc[3]);      \
    acc[4] = fmaf(dd_, b2f_lo(vv.z), acc[4]);      \
    acc[5] = fmaf(dd_, b2f_hi(vv.z), acc[5]);      \
    acc[6] = fmaf(dd_, b2f_lo(vv.w), acc[6]);      \
    acc[7] = fmaf(dd_, b2f_hi(vv.w), acc[7]);

            for (int base = e0; base < e1; base += 32) {
                const int m = min(32, e1 - base);
                int s = 0;
                float ds = 0.0f;
                if (hl < m) {
                    s = csr_src[base + hl];
                    ds = dis[s];
                }
                int j = 0;
                for (; j + 8 <= m; j += 8) {
                    uint4 vv[8];
                    float dd[8];
#pragma unroll
                    for (int q = 0; q < 8; ++q) {
                        const int sq = __shfl(s, j + q, 32);
                        dd[q] = __shfl(ds, j + q, 32);
                        vv[q] = *reinterpret_cast<const uint4*>(&hin[(size_t)sq * WIDTH + hl * 8]);
                    }
#pragma unroll
                    for (int q = 0; q < 8; ++q) { EDGE_FMA(vv[q], dd[q]) }
                }
                if (j + 4 <= m) {
                    uint4 vv[4];
                    float dd[4];
#pragma unroll
                    for (int q = 0; q < 4; ++q) {
                        const int sq = __shfl(s, j + q, 32);
                        dd[q] = __shfl(ds, j + q, 32);
                        vv[q] = *reinterpret_cast<const uint4*>(&hin[(size_t)sq * WIDTH + hl * 8]);
                    }
#pragma unroll
                    for (int q = 0; q < 4; ++q) { EDGE_FMA(vv[q], dd[q]) }
                    j += 4;
                }
                for (; j < m; ++j) {
                    const int sj = __shfl(s, j, 32);
                    const float dj = __shfl(ds, j, 32);
                    const uint4 v = *reinterpret_cast<const uint4*>(&hin[(size_t)sj * WIDTH + hl * 8]);
                    EDGE_FMA(v, dj)
                }
            }
#undef EDGE_FMA

            // y = di * acc, pack bf16, swizzled LDS write
            uint4 ob;
            ob.x = pack2(di * acc[0], di * acc[1]);
            ob.y = pack2(di * acc[2], di * acc[3]);
            ob.z = pack2(di * acc[4], di * acc[5]);
            ob.w = pack2(di * acc[6], di * acc[7]);
            const int lrow = node - m0;
            *reinterpret_cast<uint4*>(&Ys[(lrow << 8) + ((hl ^ (lrow & 7)) << 3)]) = ob;
        }
    }
    __syncthreads();

    // ---- phase 2: MFMA y@W, weights from L2 ----
    const int w = tid >> 6;
    const int l = tid & 63;

    f32x4 acc2[4][4] = {};

#pragma unroll
    for (int s = 0; s < 8; ++s) {   // K-step of 32
        bf16x8 a[4], b[4];
#pragma unroll
        for (int fr = 0; fr < 4; ++fr) {
            const int row = fr * 16 + (l & 15);
            const int slot = (s * 4 + (l >> 4)) ^ (row & 7);
            a[fr] = *reinterpret_cast<const bf16x8*>(&Ys[row * 256 + slot * 8]);
        }
#pragma unroll
        for (int fc = 0; fc < 4; ++fc) {
            const int rn = w * 64 + fc * 16 + (l & 15);
            b[fc] = *reinterpret_cast<const bf16x8*>(&WgT_l[(size_t)rn * 256 + s * 32 + (l >> 4) * 8]);
        }
#pragma unroll
        for (int fr = 0; fr < 4; ++fr)
#pragma unroll
            for (int fc = 0; fc < 4; ++fc)
                acc2[fr][fc] = __builtin_amdgcn_mfma_f32_16x16x32_bf16(a[fr], b[fc], acc2[fr][fc], 0, 0, 0);
    }

    // ---- epilogue: residual + bias, f32 h + bf16 hout ----
    const int r0 = (l >> 4) * 4;
    const int ci = l & 15;
#pragma unroll
    for (int fr = 0; fr < 4; ++fr)
#pragma unroll
        for (int fc = 0; fc < 4; ++fc) {
            const int col = w * 64 + fc * 16 + ci;
            const float bgc = bg_l[col];
#pragma unroll
            for (int r = 0; r < 4; ++r) {
                const int row = m0 + fr * 16 + r0 + r;
                const size_t p = (size_t)row * WIDTH + col;
                const float o = h[p] + bgc + acc2[fr][fc][r];
                h[p] = o;
                hout[p] = f2b(o);
            }
        }
}

// ---------------- head ----------------
__global__ __launch_bounds__(256) void k_head(const float* __restrict__ h,
                                              const int* __restrict__ center,
                                              const int* __restrict__ ptr,
                                              const float* __restrict__ Wh,
                                              const float* __restrict__ bh,
                                              float* __restrict__ out) {
    __shared__ float gs[256];
    const int g = blockIdx.x;
    const int node = center[g] + ptr[g];
    gs[threadIdx.x] = gelu_exact(h[(size_t)node * WIDTH + threadIdx.x]);
    __syncthreads();
    if (threadIdx.x < 7) {
        float acc = bh[threadIdx.x];
        for (int k = 0; k < 256; ++k)
            acc = fmaf(gs[k], Wh[threadIdx.x * 256 + k], acc);
        out[g * 7 + threadIdx.x] = acc;
    }
}

extern "C" void kernel_launch(void* const* d_in, const int* in_sizes, int n_in,
                              void* d_out, int out_size, void* d_ws, size_t ws_size,
                              hipStream_t stream) {
    const float* x      = (const float*)d_in[0];
    const int*   ei     = (const int*)d_in[1];
    const int*   center = (const int*)d_in[2];
    const int*   ptr    = (const int*)d_in[3];
    const float* Wf     = (const float*)d_in[4];
    const float* bf     = (const float*)d_in[5];
    const float* Wg     = (const float*)d_in[6];
    const float* bg     = (const float*)d_in[7];
    const float* Wh     = (const float*)d_in[8];
    const float* bh     = (const float*)d_in[9];

    const int E = in_sizes[1] / 2;       // 799744
    const int N = in_sizes[0] / 64;      // 49984
    const int B = in_sizes[2];           // 32

    char* ws = (char*)d_ws;
    size_t o = 0;
    float* h       = (float*)(ws + o); o += (size_t)N * WIDTH * 4;   // 51.2 MB
    u16*   hb0     = (u16*)  (ws + o); o += (size_t)N * WIDTH * 2;   // 25.6 MB
    u16*   hb1     = (u16*)  (ws + o); o += (size_t)N * WIDTH * 2;   // 25.6 MB
    u16*   xb      = (u16*)  (ws + o); o += (size_t)N * 64 * 2;      // 6.4 MB
    float* dis     = (float*)(ws + o); o += (size_t)N * 4;
    int*   deg     = (int*)  (ws + o); o += (size_t)N * 4;
    int*   off     = (int*)  (ws + o); o += (size_t)(N + 1) * 4;
    int*   cursor  = (int*)  (ws + o); o += (size_t)N * 4;
    int*   part    = (int*)  (ws + o); o += 1024;
    int*   csr_src = (int*)  (ws + o); o += (size_t)E * 4;           // 3.2 MB
    u16*   WgT     = (u16*)  (ws + o); o += (size_t)4 * 65536 * 2;   // 0.5 MB
    u16*   WfT     = (u16*)  (ws + o); o += (size_t)256 * 64 * 2;    // 32 KB

    const int* rowv = ei;
    const int* colv = ei + E;

    const int nb = (N + 255) / 256;   // 196
    const int eb = (E + 255) / 256;

    // CSR by destination + norm
    hipMemsetAsync(deg, 0, (size_t)N * 4, stream);
    k_hist<<<eb, 256, 0, stream>>>(colv, deg, E);
    k_scan1<<<nb, 256, 0, stream>>>(deg, off, part, dis, N);
    k_scan2<<<1, 256, 0, stream>>>(part, nb);
    k_scan3<<<nb, 256, 0, stream>>>(off, part, cursor, N, E);
    k_fill<<<eb, 256, 0, stream>>>(rowv, colv, cursor, csr_src, E);

    // bf16 weight/input prep (merged)
    const int total8 = N * 64 / 8;
    const int prep_threads = 4 * 65536 + 256 * 64 + total8;
    k_prep<<<(prep_threads + 255) / 256, 256, 0, stream>>>(Wg, Wf, x, WgT, WfT, xb, total8);

    // foot: h = gelu(xb @ WfT^T + bf) via MFMA; writes h f32 + hb0 bf16
    k_gemm_foot<64><<<N / 64, 256, 0, stream>>>(xb, WfT, bf, hb0, h);

    // fused layers, ping-pong hb0/hb1 (hin != hout: cross-block gather race otherwise)
    u16* hbuf[2] = {hb0, hb1};
    for (int l = 0; l < 4; ++l) {
        k_layer<<<N / 64, 256, 0, stream>>>(off, csr_src, dis, hbuf[l & 1],
                                            WgT + (size_t)l * 65536,
                                            bg + (size_t)l * WIDTH, h, hbuf[(l + 1) & 1]);
    }

    k_head<<<B, 256, 0, stream>>>(h, center, ptr, Wh, bh, (float*)d_out);
}

// Round 9
// 466.212 us; speedup vs baseline: 1.3292x; 1.3292x over previous
//
#include <hip/hip_runtime.h>
#include <math.h>

#define WIDTH 256
typedef unsigned short u16;
typedef unsigned int u32;
typedef __attribute__((ext_vector_type(4))) float f32x4;
typedef __attribute__((ext_vector_type(8))) short bf16x8;

__device__ __forceinline__ float gelu_exact(float v) {
    return 0.5f * v * (1.0f + erff(v * 0.70710678118654752f));
}
__device__ __forceinline__ u16 f2b(float x) {   // f32 -> bf16 RTNE
    u32 u = __builtin_bit_cast(u32, x);
    return (u16)((u + 0x7fffu + ((u >> 16) & 1u)) >> 16);
}
__device__ __forceinline__ float b2f_lo(u32 v) {
    return __builtin_bit_cast(float, v << 16);
}
__device__ __forceinline__ float b2f_hi(u32 v) {
    return __builtin_bit_cast(float, v & 0xffff0000u);
}
__device__ __forceinline__ u32 pack2(float a, float b) {
    return (u32)f2b(a) | ((u32)f2b(b) << 16);
}

// ---------------- CSR build ----------------
__global__ void k_hist(const int* __restrict__ col, int* __restrict__ deg, int E) {
    int i = blockIdx.x * blockDim.x + threadIdx.x;
    if (i < E) atomicAdd(&deg[col[i]], 1);
}

__global__ __launch_bounds__(256) void k_scan1(const int* __restrict__ deg, int* __restrict__ off,
                                               int* __restrict__ part, float* __restrict__ dis, int N) {
    __shared__ int buf[256];
    const int t = threadIdx.x;
    const int gid = blockIdx.x * 256 + t;
    const int v = (gid < N) ? deg[gid] : 0;
    if (gid < N) dis[gid] = rsqrtf(1.0f + (float)v);
    buf[t] = v;
    __syncthreads();
#pragma unroll
    for (int d = 1; d < 256; d <<= 1) {
        int add = (t >= d) ? buf[t - d] : 0;
        __syncthreads();
        buf[t] += add;
        __syncthreads();
    }
    if (gid < N) off[gid] = buf[t] - v;
    if (t == 255) part[blockIdx.x] = buf[255];
}

// fused scan-of-parts + add-base (each block redundantly scans part[] in LDS)
__global__ __launch_bounds__(256) void k_scan3(int* __restrict__ off, const int* __restrict__ part,
                                               int* __restrict__ cursor, int NB, int N, int E) {
    __shared__ int buf[256];
    const int t = threadIdx.x;
    int v = (t < NB) ? part[t] : 0;
    buf[t] = v;
    __syncthreads();
#pragma unroll
    for (int d = 1; d < 256; d <<= 1) {
        int add = (t >= d) ? buf[t - d] : 0;
        __syncthreads();
        buf[t] += add;
        __syncthreads();
    }
    const int base = (blockIdx.x == 0) ? 0 : buf[blockIdx.x - 1];   // exclusive base for this block
    const int gid = blockIdx.x * 256 + t;
    if (gid < N) {
        int o = off[gid] + base;
        off[gid] = o;
        cursor[gid] = o;
    }
    if (gid == 0) off[N] = E;
}

// csr entry = (src u16) | (bf16(dis[src]) << 16)
__global__ void k_fill(const int* __restrict__ row, const int* __restrict__ col,
                       const float* __restrict__ dis,
                       int* __restrict__ cursor, u32* __restrict__ csr, int E) {
    int i = blockIdx.x * blockDim.x + threadIdx.x;
    if (i < E) {
        const int r = row[i];
        const int pos = atomicAdd(&cursor[col[i]], 1);
        csr[pos] = (u32)(u16)r | ((u32)f2b(dis[r]) << 16);
    }
}

// ---------------- merged prep: WgT transpose + WfT copy + x->bf16 + deg zero ----------------
#define PREP_WG   (4 * 65536)
#define PREP_WF   (256 * 64)
__global__ void k_prep(const float* __restrict__ Wg, const float* __restrict__ Wf,
                       const float* __restrict__ x,
                       u16* __restrict__ WgT, u16* __restrict__ WfT,
                       u16* __restrict__ xb, int* __restrict__ deg, int total8, int N) {
    int idx = blockIdx.x * blockDim.x + threadIdx.x;
    if (idx < PREP_WG) {
        int l = idx >> 16;
        int k = (idx >> 8) & 255;
        int n = idx & 255;
        WgT[(size_t)l * 65536 + (size_t)n * 256 + k] = f2b(Wg[idx]);
    } else if (idx < PREP_WG + PREP_WF) {
        int j = idx - PREP_WG;
        WfT[j] = f2b(Wf[j]);   // Wf already [n][k]
    } else if (idx < PREP_WG + PREP_WF + total8) {
        int i = idx - (PREP_WG + PREP_WF);
        const float4 v0 = *reinterpret_cast<const float4*>(&x[(size_t)i * 8]);
        const float4 v1 = *reinterpret_cast<const float4*>(&x[(size_t)i * 8 + 4]);
        uint4 o;
        o.x = pack2(v0.x, v0.y);
        o.y = pack2(v0.z, v0.w);
        o.z = pack2(v1.x, v1.y);
        o.w = pack2(v1.z, v1.w);
        *reinterpret_cast<uint4*>(&xb[(size_t)i * 8]) = o;
    } else {
        int i = idx - (PREP_WG + PREP_WF + total8);
        if (i < N) deg[i] = 0;
    }
}

// ---------------- MFMA GEMM (round-6 verified): C[M,256] = A[M,KDIM](bf16) @ BT[256,KDIM]^T ----------------
template <int KDIM, bool FOOT>
__global__ __launch_bounds__(256) void k_gemm_mfma(const u16* __restrict__ A,
                                                   const u16* __restrict__ BT,
                                                   const float* __restrict__ bias,
                                                   u16* __restrict__ Cb,
                                                   float* __restrict__ Cf) {
    __shared__ u16 As[64 * 64];
    __shared__ u16 Bs[256 * 64];

    const int tid = threadIdx.x;
    const int w = tid >> 6;
    const int l = tid & 63;
    const int m0 = blockIdx.x * 64;

    const int lr = l >> 3;
    const int lc = l & 7;
    const int src_slot = lc ^ lr;

    f32x4 acc[4][4] = {};

#pragma unroll
    for (int ks = 0; ks < KDIM / 64; ++ks) {
        const int k0 = ks * 64;
#pragma unroll
        for (int i = 0; i < 2; ++i) {
            const u16* asrc = A + (size_t)(m0 + 16 * w + 8 * i + lr) * KDIM + k0 + src_slot * 8;
            __builtin_amdgcn_global_load_lds(
                (const __attribute__((address_space(1))) u32*)asrc,
                (__attribute__((address_space(3))) u32*)(As + (16 * w + 8 * i) * 64), 16, 0, 0);
        }
#pragma unroll
        for (int j = 0; j < 8; ++j) {
            const u16* bsrc = BT + (size_t)(64 * w + 8 * j + lr) * KDIM + k0 + src_slot * 8;
            __builtin_amdgcn_global_load_lds(
                (const __attribute__((address_space(1))) u32*)bsrc,
                (__attribute__((address_space(3))) u32*)(Bs + (64 * w + 8 * j) * 64), 16, 0, 0);
        }
        asm volatile("s_waitcnt vmcnt(0)" ::: "memory");
        __syncthreads();

        bf16x8 a[4][2], b[4][2];
#pragma unroll
        for (int fr = 0; fr < 4; ++fr) {
            const int row = fr * 16 + (l & 15);
#pragma unroll
            for (int kk = 0; kk < 2; ++kk)
                a[fr][kk] = *reinterpret_cast<const bf16x8*>(
                    &As[row * 64 + ((kk * 4 + (l >> 4)) ^ (row & 7)) * 8]);
        }
#pragma unroll
        for (int fc = 0; fc < 4; ++fc) {
            const int row = 64 * w + fc * 16 + (l & 15);
#pragma unroll
            for (int kk = 0; kk < 2; ++kk)
                b[fc][kk] = *reinterpret_cast<const bf16x8*>(
                    &Bs[row * 64 + ((kk * 4 + (l >> 4)) ^ (row & 7)) * 8]);
        }
#pragma unroll
        for (int fr = 0; fr < 4; ++fr)
#pragma unroll
            for (int fc = 0; fc < 4; ++fc) {
                acc[fr][fc] = __builtin_amdgcn_mfma_f32_16x16x32_bf16(a[fr][0], b[fc][0], acc[fr][fc], 0, 0, 0);
                acc[fr][fc] = __builtin_amdgcn_mfma_f32_16x16x32_bf16(a[fr][1], b[fc][1], acc[fr][fc], 0, 0, 0);
            }
        __syncthreads();
    }

    const int r0 = (l >> 4) * 4;
    const int ci = l & 15;
#pragma unroll
    for (int fr = 0; fr < 4; ++fr)
#pragma unroll
        for (int fc = 0; fc < 4; ++fc) {
            const int col = w * 64 + fc * 16 + ci;
#pragma unroll
            for (int r = 0; r < 4; ++r) {
                const int row = m0 + fr * 16 + r0 + r;
                if (FOOT) {
                    const float o = gelu_exact(acc[fr][fc][r] + bias[col]);
                    Cf[(size_t)row * WIDTH + col] = o;
                    Cb[(size_t)row * WIDTH + col] = f2b(o);
                } else {
                    Cb[(size_t)row * WIDTH + col] = f2b(acc[fr][fc][r]);
                }
            }
        }
}

// ---------------- channel-split aggregate: one pass handles 128 channels ----------------
// h[i][c] += bg[c] + dis[i]*( dis[i]*xl[i][c] + sum_e ds_e*xl[src_e][c] );  hb = bf16(h)
// 32-lane group per node, lane owns 4 channels (uint2 = 8B gather). Gather row = 256B ->
// working set 12.8MB, inter-reuse gap ~1.8MB < 4MB XCD L2 -> high hit rate.
__global__ __launch_bounds__(256) void k_agg(const int* __restrict__ off,
                                             const u32* __restrict__ csr,
                                             const float* __restrict__ dis,
                                             const u16* __restrict__ xlb,
                                             const float* __restrict__ bg,
                                             float* __restrict__ h,
                                             u16* __restrict__ hb, int ch0, int N) {
    const int node = (blockIdx.x * 256 + threadIdx.x) >> 5;
    if (node >= N) return;
    const int hl = threadIdx.x & 31;
    const int c = ch0 + hl * 4;
    const int e0 = off[node];
    const int e1 = off[node + 1];
    const float di = dis[node];

    float acc[4];
    // self-loop
    {
        const uint2 v = *reinterpret_cast<const uint2*>(&xlb[(size_t)node * WIDTH + c]);
        acc[0] = di * b2f_lo(v.x);
        acc[1] = di * b2f_hi(v.x);
        acc[2] = di * b2f_lo(v.y);
        acc[3] = di * b2f_hi(v.y);
    }

#define EDGE_FMA(vv, dd_)                          \
    acc[0] = fmaf(dd_, b2f_lo(vv.x), acc[0]);      \
    acc[1] = fmaf(dd_, b2f_hi(vv.x), acc[1]);      \
    acc[2] = fmaf(dd_, b2f_lo(vv.y), acc[2]);      \
    acc[3] = fmaf(dd_, b2f_hi(vv.y), acc[3]);

    for (int base = e0; base < e1; base += 32) {
        const int m = min(32, e1 - base);
        u32 ep = 0;
        if (hl < m) ep = csr[base + hl];
        int j = 0;
        for (; j + 8 <= m; j += 8) {
            uint2 vv[8];
            float dd[8];
#pragma unroll
            for (int q = 0; q < 8; ++q) {
                const u32 e = (u32)__shfl((int)ep, j + q, 32);
                dd[q] = b2f_hi(e);
                vv[q] = *reinterpret_cast<const uint2*>(&xlb[(size_t)(e & 0xffffu) * WIDTH + c]);
            }
#pragma unroll
            for (int q = 0; q < 8; ++q) { EDGE_FMA(vv[q], dd[q]) }
        }
        if (j + 4 <= m) {
            uint2 vv[4];
            float dd[4];
#pragma unroll
            for (int q = 0; q < 4; ++q) {
                const u32 e = (u32)__shfl((int)ep, j + q, 32);
                dd[q] = b2f_hi(e);
                vv[q] = *reinterpret_cast<const uint2*>(&xlb[(size_t)(e & 0xffffu) * WIDTH + c]);
            }
#pragma unroll
            for (int q = 0; q < 4; ++q) { EDGE_FMA(vv[q], dd[q]) }
            j += 4;
        }
        for (; j < m; ++j) {
            const u32 e = (u32)__shfl((int)ep, j, 32);
            const float dj = b2f_hi(e);
            const uint2 v = *reinterpret_cast<const uint2*>(&xlb[(size_t)(e & 0xffffu) * WIDTH + c]);
            EDGE_FMA(v, dj)
        }
    }
#undef EDGE_FMA

    const size_t p = (size_t)node * WIDTH + c;
    const float4 hv = *reinterpret_cast<const float4*>(&h[p]);
    const float4 bv = *reinterpret_cast<const float4*>(&bg[c]);
    float o0 = hv.x + bv.x + di * acc[0];
    float o1 = hv.y + bv.y + di * acc[1];
    float o2 = hv.z + bv.z + di * acc[2];
    float o3 = hv.w + bv.w + di * acc[3];
    float4 w0;
    w0.x = o0; w0.y = o1; w0.z = o2; w0.w = o3;
    *reinterpret_cast<float4*>(&h[p]) = w0;
    uint2 ob;
    ob.x = pack2(o0, o1);
    ob.y = pack2(o2, o3);
    *reinterpret_cast<uint2*>(&hb[p]) = ob;
}

// ---------------- head ----------------
__global__ __launch_bounds__(256) void k_head(const float* __restrict__ h,
                                              const int* __restrict__ center,
                                              const int* __restrict__ ptr,
                                              const float* __restrict__ Wh,
                                              const float* __restrict__ bh,
                                              float* __restrict__ out) {
    __shared__ float gs[256];
    const int g = blockIdx.x;
    const int node = center[g] + ptr[g];
    gs[threadIdx.x] = gelu_exact(h[(size_t)node * WIDTH + threadIdx.x]);
    __syncthreads();
    if (threadIdx.x < 7) {
        float acc = bh[threadIdx.x];
        for (int k = 0; k < 256; ++k)
            acc = fmaf(gs[k], Wh[threadIdx.x * 256 + k], acc);
        out[g * 7 + threadIdx.x] = acc;
    }
}

extern "C" void kernel_launch(void* const* d_in, const int* in_sizes, int n_in,
                              void* d_out, int out_size, void* d_ws, size_t ws_size,
                              hipStream_t stream) {
    const float* x      = (const float*)d_in[0];
    const int*   ei     = (const int*)d_in[1];
    const int*   center = (const int*)d_in[2];
    const int*   ptr    = (const int*)d_in[3];
    const float* Wf     = (const float*)d_in[4];
    const float* bf     = (const float*)d_in[5];
    const float* Wg     = (const float*)d_in[6];
    const float* bg     = (const float*)d_in[7];
    const float* Wh     = (const float*)d_in[8];
    const float* bh     = (const float*)d_in[9];

    const int E = in_sizes[1] / 2;       // 799744
    const int N = in_sizes[0] / 64;      // 49984
    const int B = in_sizes[2];           // 32

    char* ws = (char*)d_ws;
    size_t o = 0;
    float* h       = (float*)(ws + o); o += (size_t)N * WIDTH * 4;   // 51.2 MB
    u16*   hb      = (u16*)  (ws + o); o += (size_t)N * WIDTH * 2;   // 25.6 MB
    u16*   xlb     = (u16*)  (ws + o); o += (size_t)N * WIDTH * 2;   // 25.6 MB
    u16*   xb      = (u16*)  (ws + o); o += (size_t)N * 64 * 2;      // 6.4 MB
    float* dis     = (float*)(ws + o); o += (size_t)N * 4;
    int*   deg     = (int*)  (ws + o); o += (size_t)N * 4;
    int*   off     = (int*)  (ws + o); o += (size_t)(N + 1) * 4;
    int*   cursor  = (int*)  (ws + o); o += (size_t)N * 4;
    int*   part    = (int*)  (ws + o); o += 1024;
    u32*   csr     = (u32*)  (ws + o); o += (size_t)E * 4;           // 3.2 MB
    u16*   WgT     = (u16*)  (ws + o); o += (size_t)4 * 65536 * 2;   // 0.5 MB
    u16*   WfT     = (u16*)  (ws + o); o += (size_t)256 * 64 * 2;    // 32 KB

    const int* rowv = ei;
    const int* colv = ei + E;

    const int nb = (N + 255) / 256;   // 196
    const int eb = (E + 255) / 256;

    // prep (also zeroes deg) -> CSR build
    const int total8 = N * 64 / 8;
    const int prep_threads = PREP_WG + PREP_WF + total8 + N;
    k_prep<<<(prep_threads + 255) / 256, 256, 0, stream>>>(Wg, Wf, x, WgT, WfT, xb, deg, total8, N);
    k_hist<<<eb, 256, 0, stream>>>(colv, deg, E);
    k_scan1<<<nb, 256, 0, stream>>>(deg, off, part, dis, N);
    k_scan3<<<nb, 256, 0, stream>>>(off, part, cursor, nb, N, E);
    k_fill<<<eb, 256, 0, stream>>>(rowv, colv, dis, cursor, csr, E);

    // foot: h = gelu(xb @ WfT^T + bf) via MFMA; writes h f32 + hb bf16
    k_gemm_mfma<64, true><<<N / 64, 256, 0, stream>>>(xb, WfT, bf, hb, h);

    // layers: xlb = hb @ Wg[l]; then channel-split aggregate (2 passes)
    const int agg_blocks = N / 8;   // 8 nodes (32-lane groups) per block
    for (int l = 0; l < 4; ++l) {
        k_gemm_mfma<256, false><<<N / 64, 256, 0, stream>>>(hb, WgT + (size_t)l * 65536, nullptr, xlb, nullptr);
        k_agg<<<agg_blocks, 256, 0, stream>>>(off, csr, dis, xlb, bg + (size_t)l * WIDTH, h, hb, 0, N);
        k_agg<<<agg_blocks, 256, 0, stream>>>(off, csr, dis, xlb, bg + (size_t)l * WIDTH, h, hb, 128, N);
    }

    k_head<<<B, 256, 0, stream>>>(h, center, ptr, Wh, bh, (float*)d_out);
}

// Round 10
// 423.662 us; speedup vs baseline: 1.4627x; 1.1004x over previous
//
#include <hip/hip_runtime.h>
#include <math.h>

#define WIDTH 256
typedef unsigned short u16;
typedef unsigned int u32;
typedef __attribute__((ext_vector_type(4))) float f32x4;
typedef __attribute__((ext_vector_type(8))) short bf16x8;

__device__ __forceinline__ float gelu_exact(float v) {
    return 0.5f * v * (1.0f + erff(v * 0.70710678118654752f));
}
__device__ __forceinline__ u16 f2b(float x) {   // f32 -> bf16 RTNE
    u32 u = __builtin_bit_cast(u32, x);
    return (u16)((u + 0x7fffu + ((u >> 16) & 1u)) >> 16);
}
__device__ __forceinline__ float b2f_lo(u32 v) {
    return __builtin_bit_cast(float, v << 16);
}
__device__ __forceinline__ float b2f_hi(u32 v) {
    return __builtin_bit_cast(float, v & 0xffff0000u);
}
__device__ __forceinline__ u32 pack2(float a, float b) {
    return (u32)f2b(a) | ((u32)f2b(b) << 16);
}

// ---------------- CSR build ----------------
// hist also records each edge's rank within its destination bucket (atomicAdd return).
__global__ void k_hist(const int* __restrict__ col, int* __restrict__ deg,
                       int* __restrict__ rank, int E) {
    int i = blockIdx.x * blockDim.x + threadIdx.x;
    if (i < E) rank[i] = atomicAdd(&deg[col[i]], 1);
}

__global__ __launch_bounds__(256) void k_scan1(const int* __restrict__ deg, int* __restrict__ off,
                                               int* __restrict__ part, float* __restrict__ dis, int N) {
    __shared__ int buf[256];
    const int t = threadIdx.x;
    const int gid = blockIdx.x * 256 + t;
    const int v = (gid < N) ? deg[gid] : 0;
    if (gid < N) dis[gid] = rsqrtf(1.0f + (float)v);
    buf[t] = v;
    __syncthreads();
#pragma unroll
    for (int d = 1; d < 256; d <<= 1) {
        int add = (t >= d) ? buf[t - d] : 0;
        __syncthreads();
        buf[t] += add;
        __syncthreads();
    }
    if (gid < N) off[gid] = buf[t] - v;
    if (t == 255) part[blockIdx.x] = buf[255];
}

// fused scan-of-parts + add-base (each block redundantly scans part[] in LDS)
__global__ __launch_bounds__(256) void k_scan3(int* __restrict__ off, const int* __restrict__ part,
                                               int NB, int N, int E) {
    __shared__ int buf[256];
    const int t = threadIdx.x;
    int v = (t < NB) ? part[t] : 0;
    buf[t] = v;
    __syncthreads();
#pragma unroll
    for (int d = 1; d < 256; d <<= 1) {
        int add = (t >= d) ? buf[t - d] : 0;
        __syncthreads();
        buf[t] += add;
        __syncthreads();
    }
    const int base = (blockIdx.x == 0) ? 0 : buf[blockIdx.x - 1];
    const int gid = blockIdx.x * 256 + t;
    if (gid < N) off[gid] += base;
    if (gid == 0) off[N] = E;
}

// csr entry = (src u16) | (bf16(dis[src]) << 16); position = off[col] + rank (no atomic)
__global__ void k_fill(const int* __restrict__ row, const int* __restrict__ col,
                       const int* __restrict__ rank, const float* __restrict__ dis,
                       const int* __restrict__ off, u32* __restrict__ csr, int E) {
    int i = blockIdx.x * blockDim.x + threadIdx.x;
    if (i < E) {
        const int r = row[i];
        const int pos = off[col[i]] + rank[i];
        csr[pos] = (u32)(u16)r | ((u32)f2b(dis[r]) << 16);
    }
}

// ---------------- merged prep: WgT transpose + WfT copy + x->bf16 + deg zero ----------------
#define PREP_WG   (4 * 65536)
#define PREP_WF   (256 * 64)
__global__ void k_prep(const float* __restrict__ Wg, const float* __restrict__ Wf,
                       const float* __restrict__ x,
                       u16* __restrict__ WgT, u16* __restrict__ WfT,
                       u16* __restrict__ xb, int* __restrict__ deg, int total8, int N) {
    int idx = blockIdx.x * blockDim.x + threadIdx.x;
    if (idx < PREP_WG) {
        int l = idx >> 16;
        int k = (idx >> 8) & 255;
        int n = idx & 255;
        WgT[(size_t)l * 65536 + (size_t)n * 256 + k] = f2b(Wg[idx]);
    } else if (idx < PREP_WG + PREP_WF) {
        int j = idx - PREP_WG;
        WfT[j] = f2b(Wf[j]);   // Wf already [n][k]
    } else if (idx < PREP_WG + PREP_WF + total8) {
        int i = idx - (PREP_WG + PREP_WF);
        const float4 v0 = *reinterpret_cast<const float4*>(&x[(size_t)i * 8]);
        const float4 v1 = *reinterpret_cast<const float4*>(&x[(size_t)i * 8 + 4]);
        uint4 o;
        o.x = pack2(v0.x, v0.y);
        o.y = pack2(v0.z, v0.w);
        o.z = pack2(v1.x, v1.y);
        o.w = pack2(v1.z, v1.w);
        *reinterpret_cast<uint4*>(&xb[(size_t)i * 8]) = o;
    } else {
        int i = idx - (PREP_WG + PREP_WF + total8);
        if (i < N) deg[i] = 0;
    }
}

// ---------------- MFMA GEMM (round-6 verified): C[M,256] = A[M,KDIM](bf16) @ BT[256,KDIM]^T ----------------
template <int KDIM, bool FOOT>
__global__ __launch_bounds__(256) void k_gemm_mfma(const u16* __restrict__ A,
                                                   const u16* __restrict__ BT,
                                                   const float* __restrict__ bias,
                                                   u16* __restrict__ Cb,
                                                   float* __restrict__ Cf) {
    __shared__ u16 As[64 * 64];
    __shared__ u16 Bs[256 * 64];

    const int tid = threadIdx.x;
    const int w = tid >> 6;
    const int l = tid & 63;
    const int m0 = blockIdx.x * 64;

    const int lr = l >> 3;
    const int lc = l & 7;
    const int src_slot = lc ^ lr;

    f32x4 acc[4][4] = {};

#pragma unroll
    for (int ks = 0; ks < KDIM / 64; ++ks) {
        const int k0 = ks * 64;
#pragma unroll
        for (int i = 0; i < 2; ++i) {
            const u16* asrc = A + (size_t)(m0 + 16 * w + 8 * i + lr) * KDIM + k0 + src_slot * 8;
            __builtin_amdgcn_global_load_lds(
                (const __attribute__((address_space(1))) u32*)asrc,
                (__attribute__((address_space(3))) u32*)(As + (16 * w + 8 * i) * 64), 16, 0, 0);
        }
#pragma unroll
        for (int j = 0; j < 8; ++j) {
            const u16* bsrc = BT + (size_t)(64 * w + 8 * j + lr) * KDIM + k0 + src_slot * 8;
            __builtin_amdgcn_global_load_lds(
                (const __attribute__((address_space(1))) u32*)bsrc,
                (__attribute__((address_space(3))) u32*)(Bs + (64 * w + 8 * j) * 64), 16, 0, 0);
        }
        asm volatile("s_waitcnt vmcnt(0)" ::: "memory");
        __syncthreads();

        bf16x8 a[4][2], b[4][2];
#pragma unroll
        for (int fr = 0; fr < 4; ++fr) {
            const int row = fr * 16 + (l & 15);
#pragma unroll
            for (int kk = 0; kk < 2; ++kk)
                a[fr][kk] = *reinterpret_cast<const bf16x8*>(
                    &As[row * 64 + ((kk * 4 + (l >> 4)) ^ (row & 7)) * 8]);
        }
#pragma unroll
        for (int fc = 0; fc < 4; ++fc) {
            const int row = 64 * w + fc * 16 + (l & 15);
#pragma unroll
            for (int kk = 0; kk < 2; ++kk)
                b[fc][kk] = *reinterpret_cast<const bf16x8*>(
                    &Bs[row * 64 + ((kk * 4 + (l >> 4)) ^ (row & 7)) * 8]);
        }
#pragma unroll
        for (int fr = 0; fr < 4; ++fr)
#pragma unroll
            for (int fc = 0; fc < 4; ++fc) {
                acc[fr][fc] = __builtin_amdgcn_mfma_f32_16x16x32_bf16(a[fr][0], b[fc][0], acc[fr][fc], 0, 0, 0);
                acc[fr][fc] = __builtin_amdgcn_mfma_f32_16x16x32_bf16(a[fr][1], b[fc][1], acc[fr][fc], 0, 0, 0);
            }
        __syncthreads();
    }

    const int r0 = (l >> 4) * 4;
    const int ci = l & 15;
#pragma unroll
    for (int fr = 0; fr < 4; ++fr)
#pragma unroll
        for (int fc = 0; fc < 4; ++fc) {
            const int col = w * 64 + fc * 16 + ci;
#pragma unroll
            for (int r = 0; r < 4; ++r) {
                const int row = m0 + fr * 16 + r0 + r;
                if (FOOT) {
                    const float o = gelu_exact(acc[fr][fc][r] + bias[col]);
                    Cf[(size_t)row * WIDTH + col] = o;
                    Cb[(size_t)row * WIDTH + col] = f2b(o);
                } else {
                    Cb[(size_t)row * WIDTH + col] = f2b(acc[fr][fc][r]);
                }
            }
        }
}

// ---------------- channel-split aggregate, both halves in ONE dispatch ----------------
// blocks [0, nbh) do channels 0-127; blocks [nbh, 2*nbh) do channels 128-255.
// 32-lane group per node, lane owns 4 channels (uint2 = 8B gather).
__global__ __launch_bounds__(256) void k_agg(const int* __restrict__ off,
                                             const u32* __restrict__ csr,
                                             const float* __restrict__ dis,
                                             const u16* __restrict__ xlb,
                                             const float* __restrict__ bg,
                                             float* __restrict__ h,
                                             u16* __restrict__ hb, int nbh, int N) {
    int bh = blockIdx.x;
    int ch0 = 0;
    if (bh >= nbh) { ch0 = 128; bh -= nbh; }
    const int node = (bh * 256 + threadIdx.x) >> 5;
    if (node >= N) return;
    const int hl = threadIdx.x & 31;
    const int c = ch0 + hl * 4;
    const int e0 = off[node];
    const int e1 = off[node + 1];
    const float di = dis[node];

    float acc[4];
    // self-loop
    {
        const uint2 v = *reinterpret_cast<const uint2*>(&xlb[(size_t)node * WIDTH + c]);
        acc[0] = di * b2f_lo(v.x);
        acc[1] = di * b2f_hi(v.x);
        acc[2] = di * b2f_lo(v.y);
        acc[3] = di * b2f_hi(v.y);
    }

#define EDGE_FMA(vv, dd_)                          \
    acc[0] = fmaf(dd_, b2f_lo(vv.x), acc[0]);      \
    acc[1] = fmaf(dd_, b2f_hi(vv.x), acc[1]);      \
    acc[2] = fmaf(dd_, b2f_lo(vv.y), acc[2]);      \
    acc[3] = fmaf(dd_, b2f_hi(vv.y), acc[3]);

    for (int base = e0; base < e1; base += 32) {
        const int m = min(32, e1 - base);
        u32 ep = 0;
        if (hl < m) ep = csr[base + hl];
        int j = 0;
        for (; j + 8 <= m; j += 8) {
            uint2 vv[8];
            float dd[8];
#pragma unroll
            for (int q = 0; q < 8; ++q) {
                const u32 e = (u32)__shfl((int)ep, j + q, 32);
                dd[q] = b2f_hi(e);
                vv[q] = *reinterpret_cast<const uint2*>(&xlb[(size_t)(e & 0xffffu) * WIDTH + c]);
            }
#pragma unroll
            for (int q = 0; q < 8; ++q) { EDGE_FMA(vv[q], dd[q]) }
        }
        if (j + 4 <= m) {
            uint2 vv[4];
            float dd[4];
#pragma unroll
            for (int q = 0; q < 4; ++q) {
                const u32 e = (u32)__shfl((int)ep, j + q, 32);
                dd[q] = b2f_hi(e);
                vv[q] = *reinterpret_cast<const uint2*>(&xlb[(size_t)(e & 0xffffu) * WIDTH + c]);
            }
#pragma unroll
            for (int q = 0; q < 4; ++q) { EDGE_FMA(vv[q], dd[q]) }
            j += 4;
        }
        for (; j < m; ++j) {
            const u32 e = (u32)__shfl((int)ep, j, 32);
            const float dj = b2f_hi(e);
            const uint2 v = *reinterpret_cast<const uint2*>(&xlb[(size_t)(e & 0xffffu) * WIDTH + c]);
            EDGE_FMA(v, dj)
        }
    }
#undef EDGE_FMA

    const size_t p = (size_t)node * WIDTH + c;
    const float4 hv = *reinterpret_cast<const float4*>(&h[p]);
    const float4 bv = *reinterpret_cast<const float4*>(&bg[c]);
    float o0 = hv.x + bv.x + di * acc[0];
    float o1 = hv.y + bv.y + di * acc[1];
    float o2 = hv.z + bv.z + di * acc[2];
    float o3 = hv.w + bv.w + di * acc[3];
    float4 w0;
    w0.x = o0; w0.y = o1; w0.z = o2; w0.w = o3;
    *reinterpret_cast<float4*>(&h[p]) = w0;
    uint2 ob;
    ob.x = pack2(o0, o1);
    ob.y = pack2(o2, o3);
    *reinterpret_cast<uint2*>(&hb[p]) = ob;
}

// ---------------- head ----------------
__global__ __launch_bounds__(256) void k_head(const float* __restrict__ h,
                                              const int* __restrict__ center,
                                              const int* __restrict__ ptr,
                                              const float* __restrict__ Wh,
                                              const float* __restrict__ bh,
                                              float* __restrict__ out) {
    __shared__ float gs[256];
    const int g = blockIdx.x;
    const int node = center[g] + ptr[g];
    gs[threadIdx.x] = gelu_exact(h[(size_t)node * WIDTH + threadIdx.x]);
    __syncthreads();
    if (threadIdx.x < 7) {
        float acc = bh[threadIdx.x];
        for (int k = 0; k < 256; ++k)
            acc = fmaf(gs[k], Wh[threadIdx.x * 256 + k], acc);
        out[g * 7 + threadIdx.x] = acc;
    }
}

extern "C" void kernel_launch(void* const* d_in, const int* in_sizes, int n_in,
                              void* d_out, int out_size, void* d_ws, size_t ws_size,
                              hipStream_t stream) {
    const float* x      = (const float*)d_in[0];
    const int*   ei     = (const int*)d_in[1];
    const int*   center = (const int*)d_in[2];
    const int*   ptr    = (const int*)d_in[3];
    const float* Wf     = (const float*)d_in[4];
    const float* bf     = (const float*)d_in[5];
    const float* Wg     = (const float*)d_in[6];
    const float* bg     = (const float*)d_in[7];
    const float* Wh     = (const float*)d_in[8];
    const float* bh     = (const float*)d_in[9];

    const int E = in_sizes[1] / 2;       // 799744
    const int N = in_sizes[0] / 64;      // 49984
    const int B = in_sizes[2];           // 32

    char* ws = (char*)d_ws;
    size_t o = 0;
    float* h       = (float*)(ws + o); o += (size_t)N * WIDTH * 4;   // 51.2 MB
    u16*   hb      = (u16*)  (ws + o); o += (size_t)N * WIDTH * 2;   // 25.6 MB
    u16*   xlb     = (u16*)  (ws + o); o += (size_t)N * WIDTH * 2;   // 25.6 MB
    u16*   xb      = (u16*)  (ws + o); o += (size_t)N * 64 * 2;      // 6.4 MB
    float* dis     = (float*)(ws + o); o += (size_t)N * 4;
    int*   deg     = (int*)  (ws + o); o += (size_t)N * 4;
    int*   off     = (int*)  (ws + o); o += (size_t)(N + 1) * 4;
    int*   part    = (int*)  (ws + o); o += 1024;
    int*   rank    = (int*)  (ws + o); o += (size_t)E * 4;           // 3.2 MB
    u32*   csr     = (u32*)  (ws + o); o += (size_t)E * 4;           // 3.2 MB
    u16*   WgT     = (u16*)  (ws + o); o += (size_t)4 * 65536 * 2;   // 0.5 MB
    u16*   WfT     = (u16*)  (ws + o); o += (size_t)256 * 64 * 2;    // 32 KB

    const int* rowv = ei;
    const int* colv = ei + E;

    const int nb = (N + 255) / 256;   // 196
    const int eb = (E + 255) / 256;

    // prep (also zeroes deg) -> CSR build (rank from hist, fill w/o atomics)
    const int total8 = N * 64 / 8;
    const int prep_threads = PREP_WG + PREP_WF + total8 + N;
    k_prep<<<(prep_threads + 255) / 256, 256, 0, stream>>>(Wg, Wf, x, WgT, WfT, xb, deg, total8, N);
    k_hist<<<eb, 256, 0, stream>>>(colv, deg, rank, E);
    k_scan1<<<nb, 256, 0, stream>>>(deg, off, part, dis, N);
    k_scan3<<<nb, 256, 0, stream>>>(off, part, nb, N, E);
    k_fill<<<eb, 256, 0, stream>>>(rowv, colv, rank, dis, off, csr, E);

    // foot: h = gelu(xb @ WfT^T + bf) via MFMA; writes h f32 + hb bf16
    k_gemm_mfma<64, true><<<N / 64, 256, 0, stream>>>(xb, WfT, bf, hb, h);

    // layers: xlb = hb @ Wg[l]; then channel-split aggregate (both halves, one dispatch)
    const int nbh = N / 8;   // blocks per channel half
    for (int l = 0; l < 4; ++l) {
        k_gemm_mfma<256, false><<<N / 64, 256, 0, stream>>>(hb, WgT + (size_t)l * 65536, nullptr, xlb, nullptr);
        k_agg<<<2 * nbh, 256, 0, stream>>>(off, csr, dis, xlb, bg + (size_t)l * WIDTH, h, hb, nbh, N);
    }

    k_head<<<B, 256, 0, stream>>>(h, center, ptr, Wh, bh, (float*)d_out);
}